// Round 7
// baseline (353.739 us; speedup 1.0000x reference)
//
#include <hip/hip_runtime.h>
#include <cstdint>
#include <cstddef>

#define B_DIM 512
#define T_DIM 200
#define D_DIM 512
#define NPAD  208   // N padded to 13*16
#define NKG   28    // K padded to 224 = 28 groups of 8
#define NT    13    // n-tiles of 16

typedef short  short8  __attribute__((ext_vector_type(8)));
typedef float  floatx4 __attribute__((ext_vector_type(4)));

__device__ __forceinline__ unsigned short f2bf(float f) {
  unsigned int u = __float_as_uint(f);
  u += 0x7fffu + ((u >> 16) & 1u);   // round-to-nearest-even
  return (unsigned short)(u >> 16);
}
__device__ __forceinline__ float bf2f(unsigned short h) {
  return __uint_as_float(((unsigned int)h) << 16);
}

// W (200x200 fp32) -> bf16, padded 224x208, B-fragment layout [k/8][n][k%8]
__global__ void prep_w_kernel(const float* __restrict__ W,
                              unsigned short* __restrict__ wf) {
  int idx = blockIdx.x * blockDim.x + threadIdx.x;
  if (idx >= NKG * 8 * NPAD) return;
  int k = idx / NPAD;
  int n = idx - k * NPAD;
  float v = (k < T_DIM && n < T_DIM) ? W[k * T_DIM + n] : 0.0f;
  wf[((size_t)(k >> 3) * NPAD + n) * 8 + (k & 7)] = f2bf(v);
}

// Pair design: one block = 2 waves sharing a 16-row d-tile (X in LDS, staged
// half/half), with the n-range (13 tiles) split 7/6 between the waves.
// Softmax sum and weighted dot are additive over n -> combine partials in LDS.
// Per-wave: acc 28 AGPR (was 52), ~45 B-frag loads (was 91), ~26 epilogue
// rows (was 52). Shorter chains + higher occupancy attack the latency bound.
__global__ __launch_bounds__(128, 5)
void attn_kernel(const float* __restrict__ X,
                 const unsigned short* __restrict__ wf,
                 const float* __restrict__ bias,
                 float* __restrict__ out) {
  __shared__ __align__(16) unsigned short Xs[NKG * 16 * 8];  // 7168 B
  __shared__ float comb[2][2][16];                           // [wv][rs|part][row]

  const int tid  = threadIdx.x;
  const int wv   = tid >> 6;     // 0..1
  const int lane = tid & 63;
  const int l15  = lane & 15;
  const int g    = lane >> 4;

  const int bb = blockIdx.x >> 5;          // batch item
  const int d0 = (blockIdx.x & 31) << 4;   // d-tile origin

  const float* xbase = X + (size_t)bb * T_DIM * D_DIM + d0 + l15;

  // ---- staging: wave wv covers kg = wv*14 + s*4 + g, s=0..3 (s==3: g<2 only).
  // kg < 25 holds real data (T=200=25*8); kg 25..27 are zero padding.
  float cur[8], nxt[8];
  {
    const int kg = wv * 14 + g;            // <= 17, always real
    const float* p = xbase + (size_t)(kg * 8) * D_DIM;
    #pragma unroll
    for (int j = 0; j < 8; ++j) cur[j] = p[(size_t)j * D_DIM];
  }
  #pragma unroll
  for (int s = 0; s < 4; ++s) {
    if (s < 3) {  // prefetch step s+1
      const int kg  = wv * 14 + (s + 1) * 4 + g;
      const bool wa = ((s + 1) < 3) || (g < 2);
      if (wa && kg < 25) {
        const float* p = xbase + (size_t)(kg * 8) * D_DIM;
        #pragma unroll
        for (int j = 0; j < 8; ++j) nxt[j] = p[(size_t)j * D_DIM];
      } else {
        #pragma unroll
        for (int j = 0; j < 8; ++j) nxt[j] = 0.0f;
      }
    }
    const int kg  = wv * 14 + s * 4 + g;
    const bool wa = (s < 3) || (g < 2);    // kg within this wave's 14
    if (wa) {
      int4 w;
      w.x = (int)f2bf(cur[0]) | ((int)f2bf(cur[1]) << 16);
      w.y = (int)f2bf(cur[2]) | ((int)f2bf(cur[3]) << 16);
      w.z = (int)f2bf(cur[4]) | ((int)f2bf(cur[5]) << 16);
      w.w = (int)f2bf(cur[6]) | ((int)f2bf(cur[7]) << 16);
      *(int4*)&Xs[((kg * 16) + l15) * 8] = w;  // ds_write_b128
    }
    #pragma unroll
    for (int j = 0; j < 8; ++j) cur[j] = nxt[j];
  }
  __syncthreads();

  // ---- K-loop: full K, this wave's n-half. nt = nt0 + i, i < ntc.
  const int nt0 = wv * 7;
  const int ntc = 7 - wv;   // wave0: 7 tiles, wave1: 6
  floatx4 acc[7];
  #pragma unroll
  for (int i = 0; i < 7; ++i) acc[i] = (floatx4){0.f, 0.f, 0.f, 0.f};

  #pragma unroll
  for (int ks = 0; ks < 7; ++ks) {
    const int kg = ks * 4 + g;
    short8 a = *(const short8*)&Xs[((kg * 16) + l15) * 8];
    const unsigned short* wp = wf + ((size_t)kg * NPAD + nt0 * 16 + l15) * 8;
    #pragma unroll
    for (int i = 0; i < 7; ++i) {
      if (i < ntc) {
        short8 bfr = *(const short8*)(wp + i * 16 * 8);
        acc[i] = __builtin_amdgcn_mfma_f32_16x16x32_bf16(a, bfr, acc[i], 0, 0, 0);
      }
    }
  }

  // ---- fused epilogue over this wave's n-half: p = exp(tanh(z)); tanh
  // bounded => no softmax max pass. C/D: col=lane&15 (t), row m = g*4+r.
  float part[4] = {0.f, 0.f, 0.f, 0.f};
  float rs[4]   = {0.f, 0.f, 0.f, 0.f};
  #pragma unroll
  for (int i = 0; i < 7; ++i) {
    if (i < ntc) {
      const int t = (nt0 + i) * 16 + l15;
      const bool valid = (t < T_DIM);
      const float bvn = valid ? bias[t] : 0.0f;
      const unsigned short* xp = &Xs[((t >> 3) * 16) * 8 + (t & 7)];
      #pragma unroll
      for (int r = 0; r < 4; ++r) {
        if (valid) {
          float z  = acc[i][r] + bvn;
          float e  = __expf(2.0f * z);              // tanh = 1 - 2/(e^{2z}+1)
          float th = 1.0f - __fdividef(2.0f, e + 1.0f);
          float p  = __expf(th);
          rs[r]   += p;
          part[r] += p * bf2f(xp[(g * 4 + r) * 8]); // X[t][d0+g*4+r]
        }
      }
    }
  }
  // reduce over the 16 t-lanes (each (g,r) is a distinct output row)
  #pragma unroll
  for (int off = 1; off <= 8; off <<= 1)
    #pragma unroll
    for (int r = 0; r < 4; ++r) {
      part[r] += __shfl_xor(part[r], off, 16);
      rs[r]   += __shfl_xor(rs[r],   off, 16);
    }

  if (l15 == 0) {
    #pragma unroll
    for (int r = 0; r < 4; ++r) {
      comb[wv][0][g * 4 + r] = rs[r];
      comb[wv][1][g * 4 + r] = part[r];
    }
  }
  __syncthreads();

  if (wv == 0 && lane < 16) {
    float rsum = comb[0][0][lane] + comb[1][0][lane];
    float psum = comb[0][1][lane] + comb[1][1][lane];
    out[(size_t)bb * D_DIM + d0 + lane] = psum * __frcp_rn(rsum);
  }
}

extern "C" void kernel_launch(void* const* d_in, const int* in_sizes, int n_in,
                              void* d_out, int out_size, void* d_ws, size_t ws_size,
                              hipStream_t stream) {
  const float* X  = (const float*)d_in[0];
  const float* W  = (const float*)d_in[1];
  const float* bs = (const float*)d_in[2];
  float* out = (float*)d_out;
  unsigned short* wf = (unsigned short*)d_ws;  // needs 224*208*2 = 93,184 B

  const int wtot = NKG * 8 * NPAD;
  hipLaunchKernelGGL(prep_w_kernel, dim3((wtot + 255) / 256), dim3(256), 0, stream,
                     W, wf);
  // 16384 blocks = 512 b * 32 d-tiles; 2 paired waves per block
  hipLaunchKernelGGL(attn_kernel, dim3(B_DIM * 32), dim3(128), 0, stream,
                     X, wf, bs, out);
}